// Round 1
// baseline (110.841 us; speedup 1.0000x reference)
//
#include <hip/hip_runtime.h>
#include <math.h>

// Problem: B=4096 batches, C=128 classes.
//   p = softmax(mu[b])                                  [C]
//   sigma_y[i,l] = p_i p_l (sigma[i,l] - r[l] - c[i] + s)
//   r = p^T sigma, c = sigma p, s = p^T sigma p
// Memory-bound streaming: read sigma once, write sigma_y once.

#define C_DIM   128
#define C4      32          // C/4
#define TPB     256
#define F4_PB   4096        // C*C/4 float4 per batch
#define KIT     16          // F4_PB / TPB

__global__ __launch_bounds__(TPB) void vdp_softmax_kernel(
    const float* __restrict__ mu,
    const float* __restrict__ sigma,
    float* __restrict__ out_p,
    float* __restrict__ out_sy)
{
    const int b    = blockIdx.x;
    const int t    = threadIdx.x;
    const int lane = t & 63;
    const int wave = t >> 6;
    const int colg = t & 31;   // this thread's 4 columns: 4*colg .. 4*colg+3
    const int rowg = t >> 5;   // this thread's rows: rowg + 8k, k=0..15

    __shared__ float lds_p[C_DIM];
    __shared__ float lds_c[C_DIM];
    __shared__ float lds_r[C_DIM];
    __shared__ float lds_rpart[4][C_DIM];
    __shared__ float lds_red[4];

    // ---- issue all sigma loads early (independent of softmax) ----
    const float4* sig4 = (const float4*)sigma + (size_t)b * F4_PB;
    float4 v[KIT];
#pragma unroll
    for (int k = 0; k < KIT; ++k)
        v[k] = sig4[t + TPB * k];   // row = rowg+8k, cols = 4*colg..+3

    // ---- softmax over mu[b, 0:128] ----
    float x = (t < C_DIM) ? mu[(size_t)b * C_DIM + t] : -INFINITY;
    float m = x;
#pragma unroll
    for (int off = 32; off >= 1; off >>= 1)
        m = fmaxf(m, __shfl_xor(m, off, 64));
    if (lane == 0) lds_red[wave] = m;
    __syncthreads();
    float gmax = fmaxf(fmaxf(lds_red[0], lds_red[1]),
                       fmaxf(lds_red[2], lds_red[3]));
    float e = (t < C_DIM) ? expf(x - gmax) : 0.0f;
    float ssum = e;
#pragma unroll
    for (int off = 32; off >= 1; off >>= 1)
        ssum += __shfl_xor(ssum, off, 64);
    __syncthreads();                 // all waves done reading lds_red (gmax)
    if (lane == 0) lds_red[wave] = ssum;
    __syncthreads();
    float gsum = lds_red[0] + lds_red[1] + lds_red[2] + lds_red[3];
    float pv = e / gsum;
    if (t < C_DIM) {
        lds_p[t] = pv;
        out_p[(size_t)b * C_DIM + t] = pv;
    }
    __syncthreads();

    const float4 pcol = *(const float4*)&lds_p[4 * colg];

    // ---- partial r (per-column, weighted by p_row) and c (per-row dot) ----
    float4 pr = make_float4(0.f, 0.f, 0.f, 0.f);
    float  pc[KIT];
#pragma unroll
    for (int k = 0; k < KIT; ++k) {
        const int row = rowg + 8 * k;
        const float prow = lds_p[row];       // broadcast within half-wave
        const float4 vk = v[k];
        pr.x += prow * vk.x;
        pr.y += prow * vk.y;
        pr.z += prow * vk.z;
        pr.w += prow * vk.w;
        pc[k] = vk.x * pcol.x + vk.y * pcol.y + vk.z * pcol.z + vk.w * pcol.w;
    }

    // r: combine lane ^ 32 (rowg pairs within a wave), then 4 wave partials
    pr.x += __shfl_xor(pr.x, 32, 64);
    pr.y += __shfl_xor(pr.y, 32, 64);
    pr.z += __shfl_xor(pr.z, 32, 64);
    pr.w += __shfl_xor(pr.w, 32, 64);
    if (lane < 32)
        *(float4*)&lds_rpart[wave][4 * colg] = pr;

    // c: reduce across the 32 lanes of each half-wave (all 32 column groups)
#pragma unroll
    for (int off = 1; off <= 16; off <<= 1) {
#pragma unroll
        for (int k = 0; k < KIT; ++k)
            pc[k] += __shfl_xor(pc[k], off, 64);
    }
    if ((lane & 31) == 0) {
#pragma unroll
        for (int k = 0; k < KIT; ++k)
            lds_c[rowg + 8 * k] = pc[k];
    }
    __syncthreads();

    if (t < C_DIM)
        lds_r[t] = lds_rpart[0][t] + lds_rpart[1][t] +
                   lds_rpart[2][t] + lds_rpart[3][t];
    __syncthreads();

    // ---- s = sum_i p_i c_i ----
    float sval = (t < C_DIM) ? lds_p[t] * lds_c[t] : 0.0f;
#pragma unroll
    for (int off = 32; off >= 1; off >>= 1)
        sval += __shfl_xor(sval, off, 64);
    if (lane == 0) lds_red[wave] = sval;
    __syncthreads();
    const float s = lds_red[0] + lds_red[1] + lds_red[2] + lds_red[3];

    // ---- output ----
    const float4 r4 = *(const float4*)&lds_r[4 * colg];
    float4* out4 = (float4*)out_sy + (size_t)b * F4_PB;
#pragma unroll
    for (int k = 0; k < KIT; ++k) {
        const int row = rowg + 8 * k;
        const float prow = lds_p[row];
        const float base = s - lds_c[row];
        const float4 vk = v[k];
        float4 o;
        o.x = prow * pcol.x * (vk.x - r4.x + base);
        o.y = prow * pcol.y * (vk.y - r4.y + base);
        o.z = prow * pcol.z * (vk.z - r4.z + base);
        o.w = prow * pcol.w * (vk.w - r4.w + base);
        out4[t + TPB * k] = o;
    }
}

extern "C" void kernel_launch(void* const* d_in, const int* in_sizes, int n_in,
                              void* d_out, int out_size, void* d_ws, size_t ws_size,
                              hipStream_t stream) {
    const float* mu    = (const float*)d_in[0];
    const float* sigma = (const float*)d_in[1];
    float* out_p  = (float*)d_out;                  // [B, C]
    const int B = in_sizes[0] / C_DIM;
    float* out_sy = out_p + (size_t)B * C_DIM;      // [B, C, C]

    vdp_softmax_kernel<<<B, TPB, 0, stream>>>(mu, sigma, out_p, out_sy);
}

// Round 3
// 91.455 us; speedup vs baseline: 1.2120x; 1.2120x over previous
//
#include <hip/hip_runtime.h>
#include <math.h>

// B=4096 batches, C=128 classes.
//   p = softmax(mu[b])
//   sigma_y[i,l] = p_i p_l (sigma[i,l] - r[l] - c[i] + s)
//   r = p^T sigma, c = sigma p, s = p^T sigma p
// Streaming memory-bound: sigma read once, sigma_y written once.
// TPB=1024 (16 waves), KIT=4 float4/thread -> low VGPR -> 8 waves/SIMD.

#define C_DIM   128
#define TPB     1024
#define F4_PB   4096        // C*C/4 float4 per batch
#define KIT     4           // F4_PB / TPB

typedef float f4 __attribute__((ext_vector_type(4)));   // nontemporal-compatible

__global__ __launch_bounds__(TPB, 8) void vdp_softmax_kernel(
    const float* __restrict__ mu,
    const float* __restrict__ sigma,
    float* __restrict__ out_p,
    float* __restrict__ out_sy)
{
    const int b    = blockIdx.x;
    const int t    = threadIdx.x;
    const int lane = t & 63;
    const int wave = t >> 6;    // 0..15
    const int colg = t & 31;    // columns 4*colg .. 4*colg+3
    const int rowg = t >> 5;    // 0..31; rows rowg + 32k, k=0..3

    __shared__ float lds_p[C_DIM];
    __shared__ float lds_c[C_DIM];
    __shared__ float lds_r[C_DIM];
    __shared__ float lds_rpart[16][C_DIM];
    __shared__ float lds_red[4];

    // ---- issue all sigma loads early (independent of softmax) ----
    const f4* sig4 = (const f4*)sigma + (size_t)b * F4_PB;
    f4 v[KIT];
#pragma unroll
    for (int k = 0; k < KIT; ++k)
        v[k] = __builtin_nontemporal_load(&sig4[t + TPB * k]);

    // ---- softmax over mu[b, 0:128] on waves 0,1 ----
    float x = 0.f, e = 0.f;
    if (wave < 2) {
        x = mu[(size_t)b * C_DIM + t];
        float m = x;
#pragma unroll
        for (int off = 32; off >= 1; off >>= 1)
            m = fmaxf(m, __shfl_xor(m, off, 64));
        if (lane == 0) lds_red[wave] = m;
    }
    __syncthreads();
    if (wave < 2) {
        const float gmax = fmaxf(lds_red[0], lds_red[1]);
        e = expf(x - gmax);
        float ssum = e;
#pragma unroll
        for (int off = 32; off >= 1; off >>= 1)
            ssum += __shfl_xor(ssum, off, 64);
        if (lane == 0) lds_red[2 + wave] = ssum;
    }
    __syncthreads();
    if (wave < 2) {
        const float pv = e / (lds_red[2] + lds_red[3]);
        lds_p[t] = pv;
        out_p[(size_t)b * C_DIM + t] = pv;
    }
    __syncthreads();

    const f4 pcol = *(const f4*)&lds_p[4 * colg];

    // ---- partial r (per-column, p-weighted) and c (per-row dot) ----
    f4 pr = (f4)(0.f);
    float pc[KIT];
#pragma unroll
    for (int k = 0; k < KIT; ++k) {
        const float prow = lds_p[rowg + 32 * k];   // broadcast per half-wave
        const f4 vk = v[k];
        pr += prow * vk;
        pc[k] = vk.x * pcol.x + vk.y * pcol.y + vk.z * pcol.z + vk.w * pcol.w;
    }

    // r: lanes l and l+32 share colg (rowg pair) -> combine, then 16 wave partials
    pr.x += __shfl_xor(pr.x, 32, 64);
    pr.y += __shfl_xor(pr.y, 32, 64);
    pr.z += __shfl_xor(pr.z, 32, 64);
    pr.w += __shfl_xor(pr.w, 32, 64);
    if (lane < 32)
        *(f4*)&lds_rpart[wave][4 * colg] = pr;

    // c: each half-wave owns one rowg; reduce its 32 column groups
#pragma unroll
    for (int off = 1; off <= 16; off <<= 1) {
#pragma unroll
        for (int k = 0; k < KIT; ++k)
            pc[k] += __shfl_xor(pc[k], off, 64);
    }
    if ((lane & 31) == 0) {
#pragma unroll
        for (int k = 0; k < KIT; ++k)
            lds_c[rowg + 32 * k] = pc[k];   // each row written exactly once
    }
    __syncthreads();

    if (t < C_DIM) {
        float rsum = 0.f;
#pragma unroll
        for (int w = 0; w < 16; ++w)
            rsum += lds_rpart[w][t];
        lds_r[t] = rsum;
    }

    // ---- s = sum_i p_i c_i (waves 0,1) ----
    float sval = (t < C_DIM) ? lds_p[t] * lds_c[t] : 0.f;
    if (wave < 2) {
#pragma unroll
        for (int off = 32; off >= 1; off >>= 1)
            sval += __shfl_xor(sval, off, 64);
        if (lane == 0) lds_red[wave] = sval;
    }
    __syncthreads();
    const float s = lds_red[0] + lds_red[1];

    // ---- output ----
    const f4 r4 = *(const f4*)&lds_r[4 * colg];
    f4* out4 = (f4*)out_sy + (size_t)b * F4_PB;
#pragma unroll
    for (int k = 0; k < KIT; ++k) {
        const int row = rowg + 32 * k;
        const float pp   = lds_p[row];
        const float base = s - lds_c[row];
        const f4 vk = v[k];
        f4 o;
        o.x = pp * pcol.x * (vk.x - r4.x + base);
        o.y = pp * pcol.y * (vk.y - r4.y + base);
        o.z = pp * pcol.z * (vk.z - r4.z + base);
        o.w = pp * pcol.w * (vk.w - r4.w + base);
        __builtin_nontemporal_store(o, &out4[t + TPB * k]);
    }
}

extern "C" void kernel_launch(void* const* d_in, const int* in_sizes, int n_in,
                              void* d_out, int out_size, void* d_ws, size_t ws_size,
                              hipStream_t stream) {
    const float* mu    = (const float*)d_in[0];
    const float* sigma = (const float*)d_in[1];
    float* out_p  = (float*)d_out;                  // [B, C]
    const int B = in_sizes[0] / C_DIM;
    float* out_sy = out_p + (size_t)B * C_DIM;      // [B, C, C]

    vdp_softmax_kernel<<<B, TPB, 0, stream>>>(mu, sigma, out_p, out_sy);
}